// Round 7
// baseline (12498.023 us; speedup 1.0000x reference)
//
#include <hip/hip_runtime.h>
#include <math.h>

// HeterogeneousGNN fused kernel for MI355X (gfx950) — round 7.
// R1-R6 lesson: this toolchain pins the kernel at 128 arch-VGPRs no matter
// which launch-bounds/waves-per-eu spelling is used; acc[2][2](64 regs) held
// across GEMM1 forced ~350 MB/dispatch of scratch spill traffic. Fix: 1024
// threads (16 waves). GEMM2 wave tile 64u x 32o -> acc[2] f32x16 = 32 regs;
// GEMM1 tile 32x32 (gacc 16, wreg 32). Peak demand ~116 < 128 -> no spills.
// LDS: H 64K + Gc dbuf 2x32K + stats 8K = 136 KB, 1 block/CU, 4 waves/SIMD.
// Partial unrolls (no sched_barriers) bound the load-hoist window.

typedef float  f32x4  __attribute__((ext_vector_type(4)));
typedef float  f32x16 __attribute__((ext_vector_type(16)));
typedef short  s16x8  __attribute__((ext_vector_type(8)));
typedef __bf16 bf16x8 __attribute__((ext_vector_type(8)));

#define NNODE 256
#define DIMF  128
#define GB    65536    // Gc region byte offset (2 x 32768)
#define SB    131072   // stats region byte offset (8 KB)

__device__ __forceinline__ unsigned short f2bf(float f) {
  unsigned int u = __builtin_bit_cast(unsigned int, f);
  u = (u + 0x7fffu + ((u >> 16) & 1u)) >> 16;   // round-to-nearest-even
  return (unsigned short)u;
}
__device__ __forceinline__ float bf2f(unsigned short h) {
  return __builtin_bit_cast(float, (unsigned int)h << 16);
}

// H: [256 v][128 d] bf16; XOR by (v&15) -> 32-row column reads 2-way (free).
__device__ __forceinline__ int haddr(int v, int d) {
  return v * 256 + ((d * 2) ^ ((v & 15) << 4));
}
// Gc^T: [128 o][128 vrel] bf16 (256 B rows), double-buffered; XOR by (o&15).
__device__ __forceinline__ int gaddr(int o, int vr, int buf) {
  return GB + buf * 32768 + o * 256 + ((vr * 2) ^ ((o & 15) << 4));
}

#define MFMA32(a, b, c) __builtin_amdgcn_mfma_f32_32x32x16_bf16( \
    __builtin_bit_cast(bf16x8, (a)), __builtin_bit_cast(bf16x8, (b)), (c), 0, 0, 0)

// ---- prep: build fragment-ordered A3 and W3 (bf16) ----
// A3[h][ut 0..7][vt 0..15][lane][j] = Ac_h[u=ut*32+(lane&31)][v=vt*16+(lane>>5)*8+j]
// W3[hw 0..5][ot 0..3][kt 0..7][lane][j] = W_hw[o=ot*32+(lane&31)][d=kt*16+(lane>>5)*8+j]
__global__ void prep_kernel(const float* __restrict__ alp, const float* __restrict__ aln,
                            const float* __restrict__ wp,  const float* __restrict__ wn,
                            unsigned short* __restrict__ A3, unsigned short* __restrict__ W3) {
  int idx = blockIdx.x * 512 + threadIdx.x;     // 229376 threads total
  if (idx < 131072) {
    int j = idx & 7, lane = (idx >> 3) & 63, vt = (idx >> 9) & 15,
        ut = (idx >> 13) & 7, h = (idx >> 16) & 1;
    int u = ut * 32 + (lane & 31);
    int v = vt * 16 + (lane >> 5) * 8 + j;
    int s = u * 256 + v;
    float ap = 1.f / (1.f + expf(-alp[s]));
    float an = 1.f / (1.f + expf(-aln[s]));
    bool  m  = ap > an;
    float val = h ? (m ? 0.f : -an) : (m ? ap : 0.f);   // neg sign folded
    A3[idx] = f2bf(val);
  } else {
    int k = idx - 131072;                       // 0 .. 98303
    int j = k & 7, lane = (k >> 3) & 63, kt = (k >> 9) & 7,
        ot = (k >> 12) & 3, hw = (k >> 14);     // hw = l*2+h
    int o = ot * 32 + (lane & 31);
    int d = kt * 16 + (lane >> 5) * 8 + j;
    const float* src = (hw & 1) ? wn : wp;
    W3[k] = f2bf(src[(hw >> 1) * 16384 + o * 128 + d]);
  }
}

__global__ __launch_bounds__(1024, 1) void gnn_kernel(
    const float* __restrict__ X,
    const unsigned short* __restrict__ A3,
    const unsigned short* __restrict__ W3,
    const float* __restrict__ ln_g, const float* __restrict__ ln_b,
    const float* __restrict__ ro_g, const float* __restrict__ ro_b,
    float* __restrict__ out) {
  extern __shared__ char smem[];
  const int tid  = threadIdx.x;
  const int wid  = tid >> 6;        // 0..15
  const int lane = tid & 63;
  const int l31  = lane & 31;
  const int hi   = lane >> 5;
  const int b    = blockIdx.x;
  const int rg   = wid >> 2;        // 0..3: GEMM1 v-tile(32) / GEMM2 u-group(64)
  const int cg   = wid & 3;         // 0..3: o-tile(32), both phases

  // ---- stage H = bf16(X[b]) into LDS ----
  {
    const float4* Xb = (const float4*)(X + (size_t)b * NNODE * DIMF);
#pragma unroll
    for (int i = 0; i < 8; ++i) {
      int idx = tid + i * 1024;                // 8192 float4 chunks
      int v = idx >> 5, d = (idx & 31) * 4;
      float4 f = Xb[idx];
      ushort4 p;
      p.x = f2bf(f.x); p.y = f2bf(f.y); p.z = f2bf(f.z); p.w = f2bf(f.w);
      *(ushort4*)(smem + haddr(v, d)) = p;
    }
  }
  __syncthreads();

  f32x16 acc[2];                    // 64u x 32o per wave
  for (int l = 0; l < 3; ++l) {
#pragma unroll
    for (int mt = 0; mt < 2; ++mt)
#pragma unroll
      for (int r = 0; r < 16; ++r) acc[mt][r] = 0.f;

    for (int h = 0; h < 2; ++h) {
      const unsigned short* Wf  = W3 + (((l * 2 + h) * 4 + cg) * 8) * 512;
      const unsigned short* Ab0 = A3 + (size_t)((h * 8 + rg * 2 + 0) * 16) * 512;
      const unsigned short* Ab1 = A3 + (size_t)((h * 8 + rg * 2 + 1) * 16) * 512;

      // hoist this (l,h)'s W fragments into registers (reused by both chunks)
      s16x8 wreg[8];
#pragma unroll
      for (int kt = 0; kt < 8; ++kt)
        wreg[kt] = *(const s16x8*)(Wf + kt * 512 + lane * 8);

      for (int c = 0; c < 2; ++c) {            // v-chunks of 128 nodes
        const int buf = (h * 2 + c) & 1;       // Gc double-buffer parity
        // ---- GEMM1: Gc[v in 128c..][o] = H @ W^T; one 32x32 tile/wave ----
        f32x16 gacc;
#pragma unroll
        for (int r = 0; r < 16; ++r) gacc[r] = 0.f;
        const int v0 = c * 128 + rg * 32 + l31;
#pragma unroll 4
        for (int kt = 0; kt < 8; ++kt) {       // K = d = 128
          s16x8 ha = *(const s16x8*)(smem + haddr(v0, kt * 16 + hi * 8));
          gacc = MFMA32(ha, wreg[kt], gacc);
        }
        // store Gc^T[o][vrel] (buf last read before the PREVIOUS barrier)
        {
          const int og = cg * 32 + l31;        // C/D col = lane&31
#pragma unroll
          for (int rq = 0; rq < 4; ++rq) {     // rows v = (r&3)+8*(r>>2)+4*hi
            int vr = rg * 32 + rq * 8 + hi * 4;
            ushort4 p;
            p.x = f2bf(gacc[rq * 4 + 0]);
            p.y = f2bf(gacc[rq * 4 + 1]);
            p.z = f2bf(gacc[rq * 4 + 2]);
            p.w = f2bf(gacc[rq * 4 + 3]);
            *(ushort4*)(smem + gaddr(og, vr, buf)) = p;
          }
        }
        __syncthreads();                       // single barrier per chunk

        // ---- GEMM2: acc += Ac_h[u, 128c..] @ Gc[buf]; 64u x 32o /wave ----
#pragma unroll 2
        for (int kt = 0; kt < 8; ++kt) {       // K = v-chunk = 128
          s16x8 bb = *(const s16x8*)(smem + gaddr(cg * 32 + l31, kt * 16 + hi * 8, buf));
          s16x8 a0 = *(const s16x8*)(Ab0 + (c * 8 + kt) * 512 + lane * 8);
          s16x8 a1 = *(const s16x8*)(Ab1 + (c * 8 + kt) * 512 + lane * 8);
          acc[0] = MFMA32(a0, bb, acc[0]);
          acc[1] = MFMA32(a1, bb, acc[1]);
        }
      } // chunks
    } // halves

    // ---- epilogue: exact GELU + LayerNorm -> H ----
    const float lg0 = ln_g[l * 128 + cg * 32 + l31];
    const float lb0 = ln_b[l * 128 + cg * 32 + l31];
#pragma unroll
    for (int mt = 0; mt < 2; ++mt)
#pragma unroll
      for (int r = 0; r < 16; ++r) {
        float x = acc[mt][r];
        acc[mt][r] = 0.5f * x * (1.f + erff(x * 0.70710678f));
      }
    // per-row partials over this wave's 32 cols -> stats[u][cg] (f32 pair)
    float w1 = 0.f, w2 = 0.f;
#pragma unroll
    for (int mt = 0; mt < 2; ++mt)
#pragma unroll
      for (int r = 0; r < 16; ++r) {
        float s1 = acc[mt][r];
        float s2 = s1 * s1;
#pragma unroll
        for (int m = 1; m < 32; m <<= 1) {     // reduce over 32 o-cols
          s1 += __shfl_xor(s1, m);
          s2 += __shfl_xor(s2, m);
        }
        if (l31 == mt * 16 + r) { w1 = s1; w2 = s2; }
      }
    {
      int j  = l31;                            // j encodes (mt = j>>4, r = j&15)
      int uw = rg * 64 + (j >> 4) * 32 + (j & 3) + ((j >> 2) & 3) * 8 + hi * 4;
      float2 pw; pw.x = w1; pw.y = w2;
      *(float2*)(smem + SB + uw * 32 + cg * 8) = pw;
    }
    __syncthreads();
#pragma unroll
    for (int mt = 0; mt < 2; ++mt)
#pragma unroll
      for (int r = 0; r < 16; ++r) {
        int u = rg * 64 + mt * 32 + (r & 3) + ((r >> 2) & 3) * 8 + hi * 4;
        f32x4 rdA = *(const f32x4*)(smem + SB + u * 32);       // broadcast
        f32x4 rdB = *(const f32x4*)(smem + SB + u * 32 + 16);
        float mu  = (rdA[0] + rdA[2] + rdB[0] + rdB[2]) * (1.f / 128.f);
        float var = (rdA[1] + rdA[3] + rdB[1] + rdB[3]) * (1.f / 128.f) - mu * mu;
        float rs  = rsqrtf(var + 1e-5f);
        float y = (acc[mt][r] - mu) * rs * lg0 + lb0;
        *(unsigned short*)(smem + haddr(u, cg * 32 + l31)) = f2bf(y);
      }
    __syncthreads();   // H fully updated before next layer / readout
  }

  // ---- readout: mean over nodes + final LN ----
  {
    int d   = tid & 127;
    int grp = tid >> 7;                        // 0..7, 32 rows each
    float s = 0.f;
    for (int v = grp * 32; v < grp * 32 + 32; ++v)
      s += bf2f(*(const unsigned short*)(smem + haddr(v, d)));
    float* red = (float*)(smem + GB);          // Gc region is dead now
    red[grp * 128 + d] = s;
    __syncthreads();
    if (tid < 128) {
      float hv = 0.f;
#pragma unroll
      for (int g2 = 0; g2 < 8; ++g2) hv += red[g2 * 128 + tid];
      red[1024 + tid] = hv * (1.f / 256.f);
    }
    __syncthreads();
    if (tid < 64) {
      float a  = red[1024 + tid];
      float b2 = red[1024 + 64 + tid];
      float s1 = a + b2, s2 = a * a + b2 * b2;
#pragma unroll
      for (int m = 1; m < 64; m <<= 1) {
        s1 += __shfl_xor(s1, m);
        s2 += __shfl_xor(s2, m);
      }
      float mu  = s1 * (1.f / 128.f);
      float var = s2 * (1.f / 128.f) - mu * mu;
      float rs  = rsqrtf(var + 1e-5f);
      out[(size_t)b * 128 + tid]      = (a  - mu) * rs * ro_g[tid]      + ro_b[tid];
      out[(size_t)b * 128 + 64 + tid] = (b2 - mu) * rs * ro_g[64 + tid] + ro_b[64 + tid];
    }
  }
}

extern "C" void kernel_launch(void* const* d_in, const int* in_sizes, int n_in,
                              void* d_out, int out_size, void* d_ws, size_t ws_size,
                              hipStream_t stream) {
  const float* X   = (const float*)d_in[0];
  const float* alp = (const float*)d_in[1];
  const float* aln = (const float*)d_in[2];
  const float* wp  = (const float*)d_in[3];
  const float* wn  = (const float*)d_in[4];
  const float* lng = (const float*)d_in[5];
  const float* lnb = (const float*)d_in[6];
  const float* rog = (const float*)d_in[7];
  const float* rob = (const float*)d_in[8];
  float* out = (float*)d_out;

  unsigned short* A3 = (unsigned short*)d_ws;          // 131072 bf16 = 256 KB
  unsigned short* W3 = A3 + 131072;                    //  98304 bf16 = 192 KB

  (void)hipFuncSetAttribute(reinterpret_cast<const void*>(gnn_kernel),
                            hipFuncAttributeMaxDynamicSharedMemorySize, 139264);

  prep_kernel<<<448, 512, 0, stream>>>(alp, aln, wp, wn, A3, W3);
  gnn_kernel<<<2048, 1024, 139264, stream>>>(X, A3, W3, lng, lnb, rog, rob, out);
}

// Round 8
// 6879.507 us; speedup vs baseline: 1.8167x; 1.8167x over previous
//
#include <hip/hip_runtime.h>
#include <math.h>

// HeterogeneousGNN fused kernel for MI355X (gfx950) — round 8.
// R2-R7 decode: 512-thr kernels are HARD-CAPPED at 128 arch-VGPRs (cap =
// 512/min-waves-per-EU; a 512-thr WG implies >=2 waves/EU). All prior rounds
// spilled because acc(64) was live across GEMM1 contexts. Fix: phase-separated
// algebra  out = [A_pos | -A_neg] @ [G_pos ; G_neg]  (single K=512 GEMM):
//   A: stream G_neg = H@Wn^T -> region2        (live ~75 regs)
//   B: G_pos = H@Wp^T fully in regs -> bar -> overwrite H (region1) (~90)
//   C: acc = A3cat @ [G_pos;G_neg], K=512; acc born AFTER GEMM1 dies  (~105)
//   D: GELU + LN -> new H in region1                                  (~80)
// No phase exceeds ~110 < 128 -> spill-free. LDS 128 KB, 5 barriers/layer.

typedef float  f32x4  __attribute__((ext_vector_type(4)));
typedef float  f32x16 __attribute__((ext_vector_type(16)));
typedef short  s16x8  __attribute__((ext_vector_type(8)));
typedef __bf16 bf16x8 __attribute__((ext_vector_type(8)));

#define NNODE 256
#define DIMF  128
#define R2OFF 65536

__device__ __forceinline__ unsigned short f2bf(float f) {
  unsigned int u = __builtin_bit_cast(unsigned int, f);
  u = (u + 0x7fffu + ((u >> 16) & 1u)) >> 16;   // round-to-nearest-even
  return (unsigned short)u;
}
__device__ __forceinline__ float bf2f(unsigned short h) {
  return __builtin_bit_cast(float, (unsigned int)h << 16);
}

// H: [256 v][128 d] bf16 in region1; XOR (v&15) -> column b128 reads 2-way.
__device__ __forceinline__ int haddr(int v, int d) {
  return v * 256 + ((d * 2) ^ ((v & 15) << 4));
}
// G^T: [128 o][256 v] bf16 (512 B rows, 32 slots); XOR (o&31) -> uniform
// bank load for b128 column reads (8/bank = conflict-free floor).
__device__ __forceinline__ int g1addr(int o, int v) {
  return o * 512 + ((v * 2) ^ ((o & 31) << 4));
}
__device__ __forceinline__ int g2addr(int o, int v) {
  return R2OFF + o * 512 + ((v * 2) ^ ((o & 31) << 4));
}

#define MFMA32(a, b, c) __builtin_amdgcn_mfma_f32_32x32x16_bf16( \
    __builtin_bit_cast(bf16x8, (a)), __builtin_bit_cast(bf16x8, (b)), (c), 0, 0, 0)

// ---- prep ----
// A3[ut 0..7][kt 0..31][lane][j] = Acat[u=ut*32+(lane&31)][v'=kt*16+(lane>>5)*8+j]
//   where Acat[u][v'] = v'<256 ? masked A_pos[u][v'] : masked -A_neg[u][v'-256]
// W3[hw 0..5][ot 0..3][kt 0..7][lane][j] = W_hw[o=ot*32+(lane&31)][d=kt*16+(lane>>5)*8+j]
__global__ void prep_kernel(const float* __restrict__ alp, const float* __restrict__ aln,
                            const float* __restrict__ wp,  const float* __restrict__ wn,
                            unsigned short* __restrict__ A3, unsigned short* __restrict__ W3) {
  int idx = blockIdx.x * 512 + threadIdx.x;     // 229376 threads total
  if (idx < 131072) {
    int j = idx & 7, lane = (idx >> 3) & 63, kt = (idx >> 9) & 31,
        ut = (idx >> 14) & 7;
    int u  = ut * 32 + (lane & 31);
    int vp = kt * 16 + (lane >> 5) * 8 + j;     // v' in 0..511
    int s  = u * 256 + (vp & 255);
    float ap = 1.f / (1.f + expf(-alp[s]));
    float an = 1.f / (1.f + expf(-aln[s]));
    bool  m  = ap > an;
    float val = (vp < 256) ? (m ? ap : 0.f) : (m ? 0.f : -an);
    A3[idx] = f2bf(val);
  } else {
    int k = idx - 131072;                       // 0 .. 98303
    int j = k & 7, lane = (k >> 3) & 63, kt = (k >> 9) & 7,
        ot = (k >> 12) & 3, hw = (k >> 14);     // hw = l*2 + (0=pos,1=neg)
    int o = ot * 32 + (lane & 31);
    int d = kt * 16 + (lane >> 5) * 8 + j;
    const float* src = (hw & 1) ? wn : wp;
    W3[k] = f2bf(src[(hw >> 1) * 16384 + o * 128 + d]);
  }
}

__global__ __launch_bounds__(512, 2) void gnn_kernel(
    const float* __restrict__ X,
    const unsigned short* __restrict__ A3,
    const unsigned short* __restrict__ W3,
    const float* __restrict__ ln_g, const float* __restrict__ ln_b,
    const float* __restrict__ ro_g, const float* __restrict__ ro_b,
    float* __restrict__ out) {
  extern __shared__ char smem[];
  const int tid  = threadIdx.x;
  const int wid  = tid >> 6;
  const int lane = tid & 63;
  const int l31  = lane & 31;
  const int hi   = lane >> 5;
  const int b    = blockIdx.x;
  const int otA  = wid & 3;         // phases A/B: o-tile (32)
  const int vgA  = wid >> 2;        // phases A/B: v sub-tile (0..1)
  const int rgC  = wid >> 1;        // phases C/D: u-group (64)
  const int cgC  = wid & 1;         // phases C/D: o-group (64)

  // ---- stage H = bf16(X[b]) into region1 ----
  {
    const float4* Xb = (const float4*)(X + (size_t)b * NNODE * DIMF);
#pragma unroll 4
    for (int i = 0; i < 16; ++i) {
      int idx = tid + i * 512;                 // 8192 float4 chunks
      int v = idx >> 5, d = (idx & 31) * 4;
      float4 f = Xb[idx];
      ushort4 p;
      p.x = f2bf(f.x); p.y = f2bf(f.y); p.z = f2bf(f.z); p.w = f2bf(f.w);
      *(ushort4*)(smem + haddr(v, d)) = p;
    }
  }
  __syncthreads();

  for (int l = 0; l < 3; ++l) {
    // ---- Phase A: G_neg = H @ Wn^T -> region2 (streamed per 32x32 tile) ----
    {
      const unsigned short* WfN = W3 + (((l * 2 + 1) * 4 + otA) * 8) * 512;
      s16x8 wregN[8];
#pragma unroll
      for (int kt = 0; kt < 8; ++kt)
        wregN[kt] = *(const s16x8*)(WfN + kt * 512 + lane * 8);
      const int og = otA * 32 + l31;
#pragma unroll
      for (int c = 0; c < 4; ++c) {
        f32x16 gacc;
#pragma unroll
        for (int r = 0; r < 16; ++r) gacc[r] = 0.f;
        const int v0 = c * 64 + vgA * 32 + l31;
#pragma unroll 4
        for (int kt = 0; kt < 8; ++kt) {
          s16x8 ha = *(const s16x8*)(smem + haddr(v0, kt * 16 + hi * 8));
          gacc = MFMA32(ha, wregN[kt], gacc);
        }
#pragma unroll
        for (int rq = 0; rq < 4; ++rq) {       // rows v = (r&3)+8*(r>>2)+4*hi
          int v = c * 64 + vgA * 32 + rq * 8 + hi * 4;
          ushort4 p;
          p.x = f2bf(gacc[rq * 4 + 0]);
          p.y = f2bf(gacc[rq * 4 + 1]);
          p.z = f2bf(gacc[rq * 4 + 2]);
          p.w = f2bf(gacc[rq * 4 + 3]);
          *(ushort4*)(smem + g2addr(og, v)) = p;
        }
      }
    }

    // ---- Phase B: G_pos = H @ Wp^T fully in regs, then overwrite region1 ----
    {
      const unsigned short* WfP = W3 + (((l * 2 + 0) * 4 + otA) * 8) * 512;
      f32x16 gp0, gp1, gp2, gp3;
#pragma unroll
      for (int r = 0; r < 16; ++r) { gp0[r] = 0.f; gp1[r] = 0.f; gp2[r] = 0.f; gp3[r] = 0.f; }
#pragma unroll 2
      for (int kt = 0; kt < 8; ++kt) {
        s16x8 wb = *(const s16x8*)(WfP + kt * 512 + lane * 8);
        s16x8 h0 = *(const s16x8*)(smem + haddr(  0 + vgA * 32 + l31, kt * 16 + hi * 8));
        s16x8 h1 = *(const s16x8*)(smem + haddr( 64 + vgA * 32 + l31, kt * 16 + hi * 8));
        s16x8 h2 = *(const s16x8*)(smem + haddr(128 + vgA * 32 + l31, kt * 16 + hi * 8));
        s16x8 h3 = *(const s16x8*)(smem + haddr(192 + vgA * 32 + l31, kt * 16 + hi * 8));
        gp0 = MFMA32(h0, wb, gp0);
        gp1 = MFMA32(h1, wb, gp1);
        gp2 = MFMA32(h2, wb, gp2);
        gp3 = MFMA32(h3, wb, gp3);
      }
      __syncthreads();                         // bar1: all H reads done
      const int og = otA * 32 + l31;
#pragma unroll
      for (int c = 0; c < 4; ++c) {
        const f32x16& g = (c == 0) ? gp0 : (c == 1) ? gp1 : (c == 2) ? gp2 : gp3;
#pragma unroll
        for (int rq = 0; rq < 4; ++rq) {
          int v = c * 64 + vgA * 32 + rq * 8 + hi * 4;
          ushort4 p;
          p.x = f2bf(g[rq * 4 + 0]);
          p.y = f2bf(g[rq * 4 + 1]);
          p.z = f2bf(g[rq * 4 + 2]);
          p.w = f2bf(g[rq * 4 + 3]);
          *(ushort4*)(smem + g1addr(og, v)) = p;
        }
      }
    }
    __syncthreads();                           // bar2: G_pos & G_neg ready

    // ---- Phase C: acc = A3cat @ [G_pos ; G_neg], K = 512 ----
    f32x16 acc[2][2];
#pragma unroll
    for (int mt = 0; mt < 2; ++mt)
#pragma unroll
      for (int nt = 0; nt < 2; ++nt)
#pragma unroll
        for (int r = 0; r < 16; ++r) acc[mt][nt][r] = 0.f;
    {
      const unsigned short* Ab0 = A3 + (size_t)(rgC * 2 + 0) * 32 * 512;
      const unsigned short* Ab1 = A3 + (size_t)(rgC * 2 + 1) * 32 * 512;
      const int o0 = cgC * 64 + l31;
#pragma unroll 2
      for (int kt = 0; kt < 16; ++kt) {        // K-half 1: G_pos (region1)
        s16x8 b0 = *(const s16x8*)(smem + g1addr(o0,      kt * 16 + hi * 8));
        s16x8 b1 = *(const s16x8*)(smem + g1addr(o0 + 32, kt * 16 + hi * 8));
        s16x8 a0 = *(const s16x8*)(Ab0 + kt * 512 + lane * 8);
        s16x8 a1 = *(const s16x8*)(Ab1 + kt * 512 + lane * 8);
        acc[0][0] = MFMA32(a0, b0, acc[0][0]);
        acc[0][1] = MFMA32(a0, b1, acc[0][1]);
        acc[1][0] = MFMA32(a1, b0, acc[1][0]);
        acc[1][1] = MFMA32(a1, b1, acc[1][1]);
      }
#pragma unroll 2
      for (int kt = 16; kt < 32; ++kt) {       // K-half 2: G_neg (region2)
        s16x8 b0 = *(const s16x8*)(smem + g2addr(o0,      (kt - 16) * 16 + hi * 8));
        s16x8 b1 = *(const s16x8*)(smem + g2addr(o0 + 32, (kt - 16) * 16 + hi * 8));
        s16x8 a0 = *(const s16x8*)(Ab0 + kt * 512 + lane * 8);
        s16x8 a1 = *(const s16x8*)(Ab1 + kt * 512 + lane * 8);
        acc[0][0] = MFMA32(a0, b0, acc[0][0]);
        acc[0][1] = MFMA32(a0, b1, acc[0][1]);
        acc[1][0] = MFMA32(a1, b0, acc[1][0]);
        acc[1][1] = MFMA32(a1, b1, acc[1][1]);
      }
    }
    __syncthreads();                           // bar3: G reads done

    // ---- Phase D: exact GELU + LayerNorm -> new H (region1) ----
    {
      const float lg0 = ln_g[l * 128 + cgC * 64 + l31];
      const float lg1 = ln_g[l * 128 + cgC * 64 + 32 + l31];
      const float lb0 = ln_b[l * 128 + cgC * 64 + l31];
      const float lb1 = ln_b[l * 128 + cgC * 64 + 32 + l31];
#pragma unroll
      for (int mt = 0; mt < 2; ++mt)
#pragma unroll
        for (int nt = 0; nt < 2; ++nt)
#pragma unroll
          for (int r = 0; r < 16; ++r) {
            float x = acc[mt][nt][r];
            acc[mt][nt][r] = 0.5f * x * (1.f + erff(x * 0.70710678f));
          }
      float w1 = 0.f, w2 = 0.f;
#pragma unroll
      for (int mt = 0; mt < 2; ++mt)
#pragma unroll
        for (int r = 0; r < 16; ++r) {
          float a0 = acc[mt][0][r], a1 = acc[mt][1][r];
          float s1 = a0 + a1;
          float s2 = a0 * a0 + a1 * a1;
#pragma unroll
          for (int m = 1; m < 32; m <<= 1) {   // reduce over this wave's 64 cols
            s1 += __shfl_xor(s1, m);
            s2 += __shfl_xor(s2, m);
          }
          if (l31 == mt * 16 + r) { w1 = s1; w2 = s2; }
        }
      {
        int j  = l31;                          // j encodes (mt = j>>4, r = j&15)
        int uw = rgC * 64 + (j >> 4) * 32 + (j & 3) + ((j >> 2) & 3) * 8 + hi * 4;
        float2 pw; pw.x = w1; pw.y = w2;
        *(float2*)(smem + R2OFF + uw * 16 + cgC * 8) = pw;   // stats in region2
      }
      __syncthreads();                         // bar4: stats ready
#pragma unroll
      for (int mt = 0; mt < 2; ++mt)
#pragma unroll
        for (int r = 0; r < 16; ++r) {
          int u = rgC * 64 + mt * 32 + (r & 3) + ((r >> 2) & 3) * 8 + hi * 4;
          f32x4 rd = *(const f32x4*)(smem + R2OFF + u * 16);
          float mu  = (rd[0] + rd[2]) * (1.f / 128.f);
          float var = (rd[1] + rd[3]) * (1.f / 128.f) - mu * mu;
          float rs  = rsqrtf(var + 1e-5f);
          float y0 = (acc[mt][0][r] - mu) * rs * lg0 + lb0;
          float y1 = (acc[mt][1][r] - mu) * rs * lg1 + lb1;
          *(unsigned short*)(smem + haddr(u, cgC * 64 + l31))      = f2bf(y0);
          *(unsigned short*)(smem + haddr(u, cgC * 64 + 32 + l31)) = f2bf(y1);
        }
    }
    __syncthreads();                           // bar5: H ready for next layer
  }

  // ---- readout: mean over nodes + final LN ----
  {
    int d   = tid & 127;
    int grp = tid >> 7;
    float s = 0.f;
    for (int v = grp * 64; v < grp * 64 + 64; ++v)
      s += bf2f(*(const unsigned short*)(smem + haddr(v, d)));
    float* red = (float*)(smem + R2OFF);
    red[grp * 128 + d] = s;
    __syncthreads();
    if (tid < 128) {
      float hv = (red[tid] + red[128 + tid] + red[256 + tid] + red[384 + tid]) * (1.f / 256.f);
      red[512 + tid] = hv;
    }
    __syncthreads();
    if (tid < 64) {
      float a  = red[512 + tid];
      float b2 = red[512 + 64 + tid];
      float s1 = a + b2, s2 = a * a + b2 * b2;
#pragma unroll
      for (int m = 1; m < 64; m <<= 1) {
        s1 += __shfl_xor(s1, m);
        s2 += __shfl_xor(s2, m);
      }
      float mu  = s1 * (1.f / 128.f);
      float var = s2 * (1.f / 128.f) - mu * mu;
      float rs  = rsqrtf(var + 1e-5f);
      out[(size_t)b * 128 + tid]      = (a  - mu) * rs * ro_g[tid]      + ro_b[tid];
      out[(size_t)b * 128 + 64 + tid] = (b2 - mu) * rs * ro_g[64 + tid] + ro_b[64 + tid];
    }
  }
}

extern "C" void kernel_launch(void* const* d_in, const int* in_sizes, int n_in,
                              void* d_out, int out_size, void* d_ws, size_t ws_size,
                              hipStream_t stream) {
  const float* X   = (const float*)d_in[0];
  const float* alp = (const float*)d_in[1];
  const float* aln = (const float*)d_in[2];
  const float* wp  = (const float*)d_in[3];
  const float* wn  = (const float*)d_in[4];
  const float* lng = (const float*)d_in[5];
  const float* lnb = (const float*)d_in[6];
  const float* rog = (const float*)d_in[7];
  const float* rob = (const float*)d_in[8];
  float* out = (float*)d_out;

  unsigned short* A3 = (unsigned short*)d_ws;          // 131072 bf16 = 256 KB
  unsigned short* W3 = A3 + 131072;                    //  98304 bf16 = 192 KB

  (void)hipFuncSetAttribute(reinterpret_cast<const void*>(gnn_kernel),
                            hipFuncAttributeMaxDynamicSharedMemorySize, 131072);

  prep_kernel<<<448, 512, 0, stream>>>(alp, aln, wp, wn, A3, W3);
  gnn_kernel<<<2048, 512, 131072, stream>>>(X, A3, W3, lng, lnb, rog, rob, out);
}

// Round 9
// 6702.824 us; speedup vs baseline: 1.8646x; 1.0264x over previous
//
#include <hip/hip_runtime.h>
#include <math.h>

// HeterogeneousGNN fused kernel for MI355X (gfx950) — round 9.
// K=512 phase-separated algebra (out = [A_pos|-A_neg] @ [G_pos;G_neg]) with
// EVERY accumulator set capped at 32 VGPRs (R8 lesson: 64-reg acc sets +
// f32x16 alignment fragmentation still spilled under the 128-reg ceiling).
//   A : G_neg = H@Wn^T streamed (16-reg tiles) -> region2 planes
//   b0: G_pos[:, v<128] in 32 regs; BAR; write into dead H rows 0..127
//   b1: G_pos[:, v>=128] in 32 regs; BAR; write into dead H rows 128..255
//   C0: u 0..127  : acc 32 regs; GELU+row-stats kept in regs
//   C1: u 128..255: acc 32 regs (pass0 state rides along: ~105 live)
//   D : BAR (G dead) -> stats exchange via region2 scratch -> LN -> H' in situ
// Peak live ~80-105 < 128 with >=20 slack. All K-loops unroll 2.

typedef float  f32x4  __attribute__((ext_vector_type(4)));
typedef float  f32x16 __attribute__((ext_vector_type(16)));
typedef short  s16x8  __attribute__((ext_vector_type(8)));
typedef __bf16 bf16x8 __attribute__((ext_vector_type(8)));

#define R2 65536

__device__ __forceinline__ unsigned short f2bf(float f) {
  unsigned int u = __builtin_bit_cast(unsigned int, f);
  u = (u + 0x7fffu + ((u >> 16) & 1u)) >> 16;   // round-to-nearest-even
  return (unsigned short)u;
}
__device__ __forceinline__ float bf2f(unsigned short h) {
  return __builtin_bit_cast(float, (unsigned int)h << 16);
}

// H: [256 v][128 d] bf16 in region1; XOR (v&15) -> column b128 reads 2-way.
__device__ __forceinline__ int haddr(int v, int d) {
  return v * 256 + ((d * 2) ^ ((v & 15) << 4));
}
// G planes: [plane = v>>7][128 o][128 vrel] bf16 (256 B rows, 16 slots).
__device__ __forceinline__ int gposaddr(int o, int v) {
  return ((v >> 7) * 32768) + o * 256 + (((v & 127) * 2) ^ ((o & 15) << 4));
}
__device__ __forceinline__ int gnegaddr(int o, int v) {
  return R2 + ((v >> 7) * 32768) + o * 256 + (((v & 127) * 2) ^ ((o & 15) << 4));
}

#define MFMA32(a, b, c) __builtin_amdgcn_mfma_f32_32x32x16_bf16( \
    __builtin_bit_cast(bf16x8, (a)), __builtin_bit_cast(bf16x8, (b)), (c), 0, 0, 0)

// ---- prep (same as round 8) ----
// A3[ut 0..7][kt 0..31][lane][j] = Acat[u=ut*32+(lane&31)][v'=kt*16+(lane>>5)*8+j]
//   Acat[u][v'] = v'<256 ? masked A_pos[u][v'] : masked -A_neg[u][v'-256]
// W3[hw 0..5][ot 0..3][kt 0..7][lane][j] = W_hw[o=ot*32+(lane&31)][d=kt*16+(lane>>5)*8+j]
__global__ void prep_kernel(const float* __restrict__ alp, const float* __restrict__ aln,
                            const float* __restrict__ wp,  const float* __restrict__ wn,
                            unsigned short* __restrict__ A3, unsigned short* __restrict__ W3) {
  int idx = blockIdx.x * 512 + threadIdx.x;     // 229376 threads total
  if (idx < 131072) {
    int j = idx & 7, lane = (idx >> 3) & 63, kt = (idx >> 9) & 31,
        ut = (idx >> 14) & 7;
    int u  = ut * 32 + (lane & 31);
    int vp = kt * 16 + (lane >> 5) * 8 + j;     // v' in 0..511
    int s  = u * 256 + (vp & 255);
    float ap = 1.f / (1.f + expf(-alp[s]));
    float an = 1.f / (1.f + expf(-aln[s]));
    bool  m  = ap > an;
    float val = (vp < 256) ? (m ? ap : 0.f) : (m ? 0.f : -an);
    A3[idx] = f2bf(val);
  } else {
    int k = idx - 131072;                       // 0 .. 98303
    int j = k & 7, lane = (k >> 3) & 63, kt = (k >> 9) & 7,
        ot = (k >> 12) & 3, hw = (k >> 14);     // hw = l*2 + (0=pos,1=neg)
    int o = ot * 32 + (lane & 31);
    int d = kt * 16 + (lane >> 5) * 8 + j;
    const float* src = (hw & 1) ? wn : wp;
    W3[k] = f2bf(src[(hw >> 1) * 16384 + o * 128 + d]);
  }
}

__device__ __forceinline__ void store_cd_bf16(char* base, int addr_o, int v0,
                                              const f32x16& g, int rq) {
  ushort4 p;
  p.x = f2bf(g[rq * 4 + 0]);
  p.y = f2bf(g[rq * 4 + 1]);
  p.z = f2bf(g[rq * 4 + 2]);
  p.w = f2bf(g[rq * 4 + 3]);
  (void)base; (void)addr_o; (void)v0;
  // caller computes final address; this helper only packs (kept inline below)
}

__global__ __launch_bounds__(512, 2) void gnn_kernel(
    const float* __restrict__ X,
    const unsigned short* __restrict__ A3,
    const unsigned short* __restrict__ W3,
    const float* __restrict__ ln_g, const float* __restrict__ ln_b,
    const float* __restrict__ ro_g, const float* __restrict__ ro_b,
    float* __restrict__ out) {
  extern __shared__ char smem[];
  const int tid  = threadIdx.x;
  const int wid  = tid >> 6;
  const int lane = tid & 63;
  const int l31  = lane & 31;
  const int hi   = lane >> 5;
  const int b    = blockIdx.x;
  const int otA  = wid & 3;         // GEMM1: o-tile (32)
  const int vgA  = wid >> 2;        // GEMM1: v-subgroup (0..1)
  const int utC  = wid >> 1;        // GEMM2: u-tile index within pass (0..3)
  const int ogC  = (wid & 1) * 64;  // GEMM2: o-half base

  // ---- stage H = bf16(X[b]) into region1 ----
  {
    const float4* Xb = (const float4*)(X + (size_t)b * 256 * 128);
#pragma unroll 4
    for (int i = 0; i < 16; ++i) {
      int idx = tid + i * 512;
      int v = idx >> 5, d = (idx & 31) * 4;
      float4 f = Xb[idx];
      ushort4 p;
      p.x = f2bf(f.x); p.y = f2bf(f.y); p.z = f2bf(f.z); p.w = f2bf(f.w);
      *(ushort4*)(smem + haddr(v, d)) = p;
    }
  }
  __syncthreads();

  for (int l = 0; l < 3; ++l) {
    const int og = otA * 32 + l31;

    // ---- Phase A: G_neg = H @ Wn^T -> region2 planes (streamed) ----
    {
      const unsigned short* WfN = W3 + (((l * 2 + 1) * 4 + otA) * 8) * 512;
      s16x8 wregN[8];
#pragma unroll
      for (int kt = 0; kt < 8; ++kt)
        wregN[kt] = *(const s16x8*)(WfN + kt * 512 + lane * 8);
#pragma unroll
      for (int cp = 0; cp < 2; ++cp) {       // chunk pairs {0,1},{2,3}
        f32x16 g0, g1;
#pragma unroll
        for (int r = 0; r < 16; ++r) { g0[r] = 0.f; g1[r] = 0.f; }
        const int va = cp * 128 + vgA * 32 + l31;
#pragma unroll 2
        for (int kt = 0; kt < 8; ++kt) {
          s16x8 h0 = *(const s16x8*)(smem + haddr(va,      kt * 16 + hi * 8));
          s16x8 h1 = *(const s16x8*)(smem + haddr(va + 64, kt * 16 + hi * 8));
          g0 = MFMA32(h0, wregN[kt], g0);
          g1 = MFMA32(h1, wregN[kt], g1);
        }
#pragma unroll
        for (int rq = 0; rq < 4; ++rq) {
          int v0 = cp * 128 + vgA * 32 + rq * 8 + hi * 4;
          ushort4 p;
          p.x = f2bf(g0[rq*4+0]); p.y = f2bf(g0[rq*4+1]);
          p.z = f2bf(g0[rq*4+2]); p.w = f2bf(g0[rq*4+3]);
          *(ushort4*)(smem + gnegaddr(og, v0)) = p;
          p.x = f2bf(g1[rq*4+0]); p.y = f2bf(g1[rq*4+1]);
          p.z = f2bf(g1[rq*4+2]); p.w = f2bf(g1[rq*4+3]);
          *(ushort4*)(smem + gnegaddr(og, v0 + 64)) = p;
        }
      }
    }

    // ---- Phase b: G_pos in 32-reg halves, overwriting dead H halves ----
    {
      const unsigned short* WfP = W3 + (((l * 2 + 0) * 4 + otA) * 8) * 512;
      s16x8 wregP[8];
#pragma unroll
      for (int kt = 0; kt < 8; ++kt)
        wregP[kt] = *(const s16x8*)(WfP + kt * 512 + lane * 8);

      // b0: v in [0,128)
      f32x16 p0, p1;
#pragma unroll
      for (int r = 0; r < 16; ++r) { p0[r] = 0.f; p1[r] = 0.f; }
#pragma unroll 2
      for (int kt = 0; kt < 8; ++kt) {
        s16x8 h0 = *(const s16x8*)(smem + haddr(vgA * 64 +  0 + l31, kt * 16 + hi * 8));
        s16x8 h1 = *(const s16x8*)(smem + haddr(vgA * 64 + 32 + l31, kt * 16 + hi * 8));
        p0 = MFMA32(h0, wregP[kt], p0);
        p1 = MFMA32(h1, wregP[kt], p1);
      }
      __syncthreads();                       // BAR1: all H reads of rows<128 done
#pragma unroll
      for (int rq = 0; rq < 4; ++rq) {
        int v0 = vgA * 64 + rq * 8 + hi * 4;
        ushort4 p;
        p.x = f2bf(p0[rq*4+0]); p.y = f2bf(p0[rq*4+1]);
        p.z = f2bf(p0[rq*4+2]); p.w = f2bf(p0[rq*4+3]);
        *(ushort4*)(smem + gposaddr(og, v0)) = p;
        p.x = f2bf(p1[rq*4+0]); p.y = f2bf(p1[rq*4+1]);
        p.z = f2bf(p1[rq*4+2]); p.w = f2bf(p1[rq*4+3]);
        *(ushort4*)(smem + gposaddr(og, v0 + 32)) = p;
      }
      // b1: v in [128,256)  (reads H rows 128..255, untouched)
#pragma unroll
      for (int r = 0; r < 16; ++r) { p0[r] = 0.f; p1[r] = 0.f; }
#pragma unroll 2
      for (int kt = 0; kt < 8; ++kt) {
        s16x8 h0 = *(const s16x8*)(smem + haddr(128 + vgA * 64 +  0 + l31, kt * 16 + hi * 8));
        s16x8 h1 = *(const s16x8*)(smem + haddr(128 + vgA * 64 + 32 + l31, kt * 16 + hi * 8));
        p0 = MFMA32(h0, wregP[kt], p0);
        p1 = MFMA32(h1, wregP[kt], p1);
      }
      __syncthreads();                       // BAR2: rows>=128 reads done
#pragma unroll
      for (int rq = 0; rq < 4; ++rq) {
        int v0 = 128 + vgA * 64 + rq * 8 + hi * 4;
        ushort4 p;
        p.x = f2bf(p0[rq*4+0]); p.y = f2bf(p0[rq*4+1]);
        p.z = f2bf(p0[rq*4+2]); p.w = f2bf(p0[rq*4+3]);
        *(ushort4*)(smem + gposaddr(og, v0)) = p;
        p.x = f2bf(p1[rq*4+0]); p.y = f2bf(p1[rq*4+1]);
        p.z = f2bf(p1[rq*4+2]); p.w = f2bf(p1[rq*4+3]);
        *(ushort4*)(smem + gposaddr(og, v0 + 32)) = p;
      }
    }
    __syncthreads();                         // BAR3: G_pos & G_neg complete

    // ---- Phase C pass 0: u 0..127 ----
    f32x16 a00, a01;
#pragma unroll
    for (int r = 0; r < 16; ++r) { a00[r] = 0.f; a01[r] = 0.f; }
    {
      const unsigned short* Ab = A3 + (size_t)(utC * 32) * 512;
#pragma unroll 2
      for (int kt = 0; kt < 16; ++kt) {      // K-half 1: G_pos
        int vv = kt * 16 + hi * 8;
        s16x8 b0 = *(const s16x8*)(smem + gposaddr(ogC + l31,      vv));
        s16x8 b1 = *(const s16x8*)(smem + gposaddr(ogC + 32 + l31, vv));
        s16x8 af = *(const s16x8*)(Ab + kt * 512 + lane * 8);
        a00 = MFMA32(af, b0, a00);
        a01 = MFMA32(af, b1, a01);
      }
#pragma unroll 2
      for (int kt = 16; kt < 32; ++kt) {     // K-half 2: G_neg
        int vv = (kt - 16) * 16 + hi * 8;
        s16x8 b0 = *(const s16x8*)(smem + gnegaddr(ogC + l31,      vv));
        s16x8 b1 = *(const s16x8*)(smem + gnegaddr(ogC + 32 + l31, vv));
        s16x8 af = *(const s16x8*)(Ab + kt * 512 + lane * 8);
        a00 = MFMA32(af, b0, a00);
        a01 = MFMA32(af, b1, a01);
      }
    }
    // GELU + row-stats pass0 (state stays in regs through pass1)
    float w1p0 = 0.f, w2p0 = 0.f;
#pragma unroll
    for (int q = 0; q < 16; ++q) {
      float x0 = a00[q]; x0 = 0.5f * x0 * (1.f + erff(x0 * 0.70710678f)); a00[q] = x0;
      float x1 = a01[q]; x1 = 0.5f * x1 * (1.f + erff(x1 * 0.70710678f)); a01[q] = x1;
      float s1 = x0 + x1, s2 = x0 * x0 + x1 * x1;
#pragma unroll
      for (int m = 1; m < 32; m <<= 1) { s1 += __shfl_xor(s1, m); s2 += __shfl_xor(s2, m); }
      w1p0 = (l31 == q) ? s1 : w1p0;
      w2p0 = (l31 == q) ? s2 : w2p0;
    }

    // ---- Phase C pass 1: u 128..255 ----
    f32x16 a10, a11;
#pragma unroll
    for (int r = 0; r < 16; ++r) { a10[r] = 0.f; a11[r] = 0.f; }
    {
      const unsigned short* Ab = A3 + (size_t)((4 + utC) * 32) * 512;
#pragma unroll 2
      for (int kt = 0; kt < 16; ++kt) {
        int vv = kt * 16 + hi * 8;
        s16x8 b0 = *(const s16x8*)(smem + gposaddr(ogC + l31,      vv));
        s16x8 b1 = *(const s16x8*)(smem + gposaddr(ogC + 32 + l31, vv));
        s16x8 af = *(const s16x8*)(Ab + kt * 512 + lane * 8);
        a10 = MFMA32(af, b0, a10);
        a11 = MFMA32(af, b1, a11);
      }
#pragma unroll 2
      for (int kt = 16; kt < 32; ++kt) {
        int vv = (kt - 16) * 16 + hi * 8;
        s16x8 b0 = *(const s16x8*)(smem + gnegaddr(ogC + l31,      vv));
        s16x8 b1 = *(const s16x8*)(smem + gnegaddr(ogC + 32 + l31, vv));
        s16x8 af = *(const s16x8*)(Ab + kt * 512 + lane * 8);
        a10 = MFMA32(af, b0, a10);
        a11 = MFMA32(af, b1, a11);
      }
    }
    float w1p1 = 0.f, w2p1 = 0.f;
#pragma unroll
    for (int q = 0; q < 16; ++q) {
      float x0 = a10[q]; x0 = 0.5f * x0 * (1.f + erff(x0 * 0.70710678f)); a10[q] = x0;
      float x1 = a11[q]; x1 = 0.5f * x1 * (1.f + erff(x1 * 0.70710678f)); a11[q] = x1;
      float s1 = x0 + x1, s2 = x0 * x0 + x1 * x1;
#pragma unroll
      for (int m = 1; m < 32; m <<= 1) { s1 += __shfl_xor(s1, m); s2 += __shfl_xor(s2, m); }
      w1p1 = (l31 == q) ? s1 : w1p1;
      w2p1 = (l31 == q) ? s2 : w2p1;
    }
    __syncthreads();                         // BAR4: all G reads done; LDS free

    // ---- Phase D: stats exchange + LN -> H' into region1 ----
    if (l31 < 16) {
      int rr  = (l31 & 3) + 8 * (l31 >> 2) + 4 * hi;
      int row = utC * 32 + rr;               // 0..127 (pass-local row)
      float2 pa; pa.x = w1p0; pa.y = w2p0;
      float2 pb; pb.x = w1p1; pb.y = w2p1;
      *(float2*)(smem + R2 +        (row * 2 + (wid & 1)) * 8) = pa;
      *(float2*)(smem + R2 + 2048 + (row * 2 + (wid & 1)) * 8) = pb;
    }
    __syncthreads();                         // BAR5: stats ready
    {
      const float lg0 = ln_g[l * 128 + ogC + l31];
      const float lg1 = ln_g[l * 128 + ogC + 32 + l31];
      const float lb0 = ln_b[l * 128 + ogC + l31];
      const float lb1 = ln_b[l * 128 + ogC + 32 + l31];
#pragma unroll
      for (int q = 0; q < 16; ++q) {
        int rr = (q & 3) + 8 * (q >> 2) + 4 * hi;
        int u0 = utC * 32 + rr;
        f32x4 st0 = *(const f32x4*)(smem + R2 + u0 * 16);
        f32x4 st1 = *(const f32x4*)(smem + R2 + 2048 + u0 * 16);
        float mu0  = (st0[0] + st0[2]) * (1.f / 128.f);
        float var0 = (st0[1] + st0[3]) * (1.f / 128.f) - mu0 * mu0;
        float rs0  = rsqrtf(var0 + 1e-5f);
        float mu1  = (st1[0] + st1[2]) * (1.f / 128.f);
        float var1 = (st1[1] + st1[3]) * (1.f / 128.f) - mu1 * mu1;
        float rs1  = rsqrtf(var1 + 1e-5f);
        *(unsigned short*)(smem + haddr(u0, ogC + l31)) =
            f2bf((a00[q] - mu0) * rs0 * lg0 + lb0);
        *(unsigned short*)(smem + haddr(u0, ogC + 32 + l31)) =
            f2bf((a01[q] - mu0) * rs0 * lg1 + lb1);
        *(unsigned short*)(smem + haddr(128 + u0, ogC + l31)) =
            f2bf((a10[q] - mu1) * rs1 * lg0 + lb0);
        *(unsigned short*)(smem + haddr(128 + u0, ogC + 32 + l31)) =
            f2bf((a11[q] - mu1) * rs1 * lg1 + lb1);
      }
    }
    __syncthreads();                         // BAR6: H' ready
  } // layers

  // ---- readout: mean over nodes + final LN ----
  {
    int d   = tid & 127;
    int grp = tid >> 7;
    float s = 0.f;
    for (int v = grp * 64; v < grp * 64 + 64; ++v)
      s += bf2f(*(const unsigned short*)(smem + haddr(v, d)));
    float* red = (float*)(smem + R2);
    red[grp * 128 + d] = s;
    __syncthreads();
    if (tid < 128) {
      float hv = (red[tid] + red[128 + tid] + red[256 + tid] + red[384 + tid]) * (1.f / 256.f);
      red[512 + tid] = hv;
    }
    __syncthreads();
    if (tid < 64) {
      float a  = red[512 + tid];
      float b2 = red[512 + 64 + tid];
      float s1 = a + b2, s2 = a * a + b2 * b2;
#pragma unroll
      for (int m = 1; m < 64; m <<= 1) {
        s1 += __shfl_xor(s1, m);
        s2 += __shfl_xor(s2, m);
      }
      float mu  = s1 * (1.f / 128.f);
      float var = s2 * (1.f / 128.f) - mu * mu;
      float rs  = rsqrtf(var + 1e-5f);
      out[(size_t)b * 128 + tid]      = (a  - mu) * rs * ro_g[tid]      + ro_b[tid];
      out[(size_t)b * 128 + 64 + tid] = (b2 - mu) * rs * ro_g[64 + tid] + ro_b[64 + tid];
    }
  }
}

extern "C" void kernel_launch(void* const* d_in, const int* in_sizes, int n_in,
                              void* d_out, int out_size, void* d_ws, size_t ws_size,
                              hipStream_t stream) {
  const float* X   = (const float*)d_in[0];
  const float* alp = (const float*)d_in[1];
  const float* aln = (const float*)d_in[2];
  const float* wp  = (const float*)d_in[3];
  const float* wn  = (const float*)d_in[4];
  const float* lng = (const float*)d_in[5];
  const float* lnb = (const float*)d_in[6];
  const float* rog = (const float*)d_in[7];
  const float* rob = (const float*)d_in[8];
  float* out = (float*)d_out;

  unsigned short* A3 = (unsigned short*)d_ws;          // 131072 bf16 = 256 KB
  unsigned short* W3 = A3 + 131072;                    //  98304 bf16 = 192 KB

  (void)hipFuncSetAttribute(reinterpret_cast<const void*>(gnn_kernel),
                            hipFuncAttributeMaxDynamicSharedMemorySize, 131072);

  prep_kernel<<<448, 512, 0, stream>>>(alp, aln, wp, wn, A3, W3);
  gnn_kernel<<<2048, 512, 131072, stream>>>(X, A3, W3, lng, lnb, rog, rob, out);
}

// Round 10
// 949.022 us; speedup vs baseline: 13.1694x; 7.0629x over previous
//
#include <hip/hip_runtime.h>
#include <math.h>

// HeterogeneousGNN fused kernel for MI355X (gfx950) — round 10.
// NINE-ROUND DECODE: 512-thread workgroups hard-cap this toolchain at 128
// arch-VGPRs (>=2 waves/SIMD => 512/2); every fused design needs ~185 regs ->
// permanent spill storm. Guide precedent (m97: 164 VGPR, HK: 205-256) all use
// 256-THREAD blocks. This round: 4 waves/block, one block per batch item.
//   GEMM2 wave tile 64u x 128o: acc[2][4] f32x16 = 128 regs (fits @ 256 cap)
//   GEMM1 wave tile 32v x 64o per 64-node chunk, Gc^T 16 KB single-buffered
//   LDS = H 64K + Gc 16K = 80 KB -> 2 blocks/CU (2 waves/SIMD at ~185 regs)
//   LN fully wave-local (each wave owns whole 128-col rows): shuffle-only.

typedef float  f32x4  __attribute__((ext_vector_type(4)));
typedef float  f32x16 __attribute__((ext_vector_type(16)));
typedef short  s16x8  __attribute__((ext_vector_type(8)));
typedef __bf16 bf16x8 __attribute__((ext_vector_type(8)));

#define GOFF 65536   // Gc region byte offset

__device__ __forceinline__ unsigned short f2bf(float f) {
  unsigned int u = __builtin_bit_cast(unsigned int, f);
  u = (u + 0x7fffu + ((u >> 16) & 1u)) >> 16;   // round-to-nearest-even
  return (unsigned short)u;
}
__device__ __forceinline__ float bf2f(unsigned short h) {
  return __builtin_bit_cast(float, (unsigned int)h << 16);
}

// H: [256 v][128 d] bf16; XOR (v&15) -> 32-lane column b128 reads 2-way (free).
__device__ __forceinline__ int haddr(int v, int d) {
  return v * 256 + ((d * 2) ^ ((v & 15) << 4));
}
// Gc^T: [128 o][64 v] bf16 (128-B rows, 8 slots); XOR (o&7) -> 4-way b128.
__device__ __forceinline__ int gaddr(int o, int vr) {
  return GOFF + o * 128 + ((vr * 2) ^ ((o & 7) << 4));
}

#define MFMA32(a, b, c) __builtin_amdgcn_mfma_f32_32x32x16_bf16( \
    __builtin_bit_cast(bf16x8, (a)), __builtin_bit_cast(bf16x8, (b)), (c), 0, 0, 0)

// ---- prep: fragment-ordered A3 / W3 (bf16), as in round 5/6 ----
// A3[h][ut 0..7][vt 0..15][lane][j] = Ac_h[u=ut*32+(lane&31)][v=vt*16+(lane>>5)*8+j]
// W3[hw 0..5][ot 0..3][kt 0..7][lane][j] = W_hw[o=ot*32+(lane&31)][d=kt*16+(lane>>5)*8+j]
__global__ void prep_kernel(const float* __restrict__ alp, const float* __restrict__ aln,
                            const float* __restrict__ wp,  const float* __restrict__ wn,
                            unsigned short* __restrict__ A3, unsigned short* __restrict__ W3) {
  int idx = blockIdx.x * 512 + threadIdx.x;     // 229376 threads total
  if (idx < 131072) {
    int j = idx & 7, lane = (idx >> 3) & 63, vt = (idx >> 9) & 15,
        ut = (idx >> 13) & 7, h = (idx >> 16) & 1;
    int u = ut * 32 + (lane & 31);
    int v = vt * 16 + (lane >> 5) * 8 + j;
    int s = u * 256 + v;
    float ap = 1.f / (1.f + expf(-alp[s]));
    float an = 1.f / (1.f + expf(-aln[s]));
    bool  m  = ap > an;
    float val = h ? (m ? 0.f : -an) : (m ? ap : 0.f);   // neg sign folded
    A3[idx] = f2bf(val);
  } else {
    int k = idx - 131072;                       // 0 .. 98303
    int j = k & 7, lane = (k >> 3) & 63, kt = (k >> 9) & 7,
        ot = (k >> 12) & 3, hw = (k >> 14);     // hw = l*2 + (0=pos,1=neg)
    int o = ot * 32 + (lane & 31);
    int d = kt * 16 + (lane >> 5) * 8 + j;
    const float* src = (hw & 1) ? wn : wp;
    W3[k] = f2bf(src[(hw >> 1) * 16384 + o * 128 + d]);
  }
}

__global__ __launch_bounds__(256, 1) void gnn_kernel(
    const float* __restrict__ X,
    const unsigned short* __restrict__ A3,
    const unsigned short* __restrict__ W3,
    const float* __restrict__ ln_g, const float* __restrict__ ln_b,
    const float* __restrict__ ro_g, const float* __restrict__ ro_b,
    float* __restrict__ out) {
  extern __shared__ char smem[];
  const int tid  = threadIdx.x;
  const int wid  = tid >> 6;        // 0..3
  const int lane = tid & 63;
  const int l31  = lane & 31;
  const int hi   = lane >> 5;
  const int b    = blockIdx.x;
  const int rg1  = wid >> 1;        // GEMM1: v-subtile (0..1) within chunk
  const int cg1  = wid & 1;         // GEMM1: o-half (0..1)

  // ---- stage H = bf16(X[b]) into LDS ----
  {
    const float4* Xb = (const float4*)(X + (size_t)b * 256 * 128);
#pragma unroll 8
    for (int i = 0; i < 32; ++i) {
      int idx = tid + i * 256;                 // 8192 float4 chunks
      int v = idx >> 5, d = (idx & 31) * 4;
      float4 f = Xb[idx];
      ushort4 p;
      p.x = f2bf(f.x); p.y = f2bf(f.y); p.z = f2bf(f.z); p.w = f2bf(f.w);
      *(ushort4*)(smem + haddr(v, d)) = p;
    }
  }
  __syncthreads();

  f32x16 acc[2][4];                  // wave tile: u = wid*64..+64, o = 0..128
  for (int l = 0; l < 3; ++l) {
#pragma unroll
    for (int mt = 0; mt < 2; ++mt)
#pragma unroll
      for (int nt = 0; nt < 4; ++nt)
#pragma unroll
        for (int r = 0; r < 16; ++r) acc[mt][nt][r] = 0.f;

    for (int h = 0; h < 2; ++h) {
      const unsigned short* Wb = W3 + (size_t)(((l * 2 + h) * 4 + cg1 * 2) * 8) * 512;
      const unsigned short* Ab = A3 + (size_t)((h * 8 + wid * 2) * 16) * 512;

      for (int c = 0; c < 4; ++c) {            // v-chunks of 64 nodes
        // ---- GEMM1: Gc[v in 64c..][o] = H @ W^T; wave tile 32v x 64o ----
        f32x16 g0, g1;
#pragma unroll
        for (int r = 0; r < 16; ++r) { g0[r] = 0.f; g1[r] = 0.f; }
        const int v0 = c * 64 + rg1 * 32 + l31;
#pragma unroll
        for (int kt = 0; kt < 8; ++kt) {       // K = d = 128
          s16x8 ha = *(const s16x8*)(smem + haddr(v0, kt * 16 + hi * 8));
          s16x8 w0 = *(const s16x8*)(Wb + (size_t)(0 * 8 + kt) * 512 + lane * 8);
          s16x8 w1 = *(const s16x8*)(Wb + (size_t)(1 * 8 + kt) * 512 + lane * 8);
          g0 = MFMA32(ha, w0, g0);
          g1 = MFMA32(ha, w1, g1);
        }
        __syncthreads();                       // prev chunk's GEMM2 reads done
        {
          const int og0 = cg1 * 64 + l31;      // C/D col = lane&31
#pragma unroll
          for (int rq = 0; rq < 4; ++rq) {     // rows v = (r&3)+8*(r>>2)+4*hi
            int vr = rg1 * 32 + rq * 8 + hi * 4;
            ushort4 p;
            p.x = f2bf(g0[rq*4+0]); p.y = f2bf(g0[rq*4+1]);
            p.z = f2bf(g0[rq*4+2]); p.w = f2bf(g0[rq*4+3]);
            *(ushort4*)(smem + gaddr(og0, vr)) = p;
            p.x = f2bf(g1[rq*4+0]); p.y = f2bf(g1[rq*4+1]);
            p.z = f2bf(g1[rq*4+2]); p.w = f2bf(g1[rq*4+3]);
            *(ushort4*)(smem + gaddr(og0 + 32, vr)) = p;
          }
        }
        __syncthreads();                       // Gc ready

        // ---- GEMM2: acc += Ac_h[u, 64c..] @ Gc; 64u x 128o per wave ----
#pragma unroll
        for (int kt = 0; kt < 4; ++kt) {       // K = v-chunk = 64
          s16x8 bf[4];
#pragma unroll
          for (int nt = 0; nt < 4; ++nt)
            bf[nt] = *(const s16x8*)(smem + gaddr(nt * 32 + l31, kt * 16 + hi * 8));
          s16x8 a0 = *(const s16x8*)(Ab + (size_t)(0 * 16 + c * 4 + kt) * 512 + lane * 8);
          s16x8 a1 = *(const s16x8*)(Ab + (size_t)(1 * 16 + c * 4 + kt) * 512 + lane * 8);
#pragma unroll
          for (int nt = 0; nt < 4; ++nt) {
            acc[0][nt] = MFMA32(a0, bf[nt], acc[0][nt]);
            acc[1][nt] = MFMA32(a1, bf[nt], acc[1][nt]);
          }
        }
      } // chunks
    } // halves

    // ---- epilogue: exact GELU + wave-local LayerNorm -> H ----
    {
      float lg[4], lb[4];
#pragma unroll
      for (int nt = 0; nt < 4; ++nt) {
        lg[nt] = ln_g[l * 128 + nt * 32 + l31];
        lb[nt] = ln_b[l * 128 + nt * 32 + l31];
      }
#pragma unroll
      for (int mt = 0; mt < 2; ++mt)
#pragma unroll
        for (int r = 0; r < 16; ++r) {
          float x0 = acc[mt][0][r]; x0 = 0.5f * x0 * (1.f + erff(x0 * 0.70710678f));
          float x1 = acc[mt][1][r]; x1 = 0.5f * x1 * (1.f + erff(x1 * 0.70710678f));
          float x2 = acc[mt][2][r]; x2 = 0.5f * x2 * (1.f + erff(x2 * 0.70710678f));
          float x3 = acc[mt][3][r]; x3 = 0.5f * x3 * (1.f + erff(x3 * 0.70710678f));
          acc[mt][0][r] = x0; acc[mt][1][r] = x1;
          acc[mt][2][r] = x2; acc[mt][3][r] = x3;
          float s1 = x0 + x1 + x2 + x3;
          float s2 = x0 * x0 + x1 * x1 + x2 * x2 + x3 * x3;
#pragma unroll
          for (int m = 1; m < 32; m <<= 1) {   // full row (128 cols) reduce
            s1 += __shfl_xor(s1, m);
            s2 += __shfl_xor(s2, m);
          }
          float mu  = s1 * (1.f / 128.f);
          float var = s2 * (1.f / 128.f) - mu * mu;
          float rs  = rsqrtf(var + 1e-5f);
          int u = wid * 64 + mt * 32 + (r & 3) + 8 * ((r >> 2) & 3) + 4 * hi;
#pragma unroll
          for (int nt = 0; nt < 4; ++nt) {
            float y = (acc[mt][nt][r] - mu) * rs * lg[nt] + lb[nt];
            *(unsigned short*)(smem + haddr(u, nt * 32 + l31)) = f2bf(y);
          }
        }
    }
    __syncthreads();                           // H' ready for next layer
  } // layers

  // ---- readout: mean over nodes + final LN ----
  {
    int d   = tid & 127;
    int grp = tid >> 7;                        // 0..1, 128 rows each
    float s = 0.f;
    for (int v = grp * 128; v < grp * 128 + 128; ++v)
      s += bf2f(*(const unsigned short*)(smem + haddr(v, d)));
    float* red = (float*)(smem + GOFF);
    red[grp * 128 + d] = s;
    __syncthreads();
    if (tid < 128) {
      red[256 + tid] = (red[tid] + red[128 + tid]) * (1.f / 256.f);
    }
    __syncthreads();
    if (tid < 64) {
      float a  = red[256 + tid];
      float b2 = red[256 + 64 + tid];
      float s1 = a + b2, s2 = a * a + b2 * b2;
#pragma unroll
      for (int m = 1; m < 64; m <<= 1) {
        s1 += __shfl_xor(s1, m);
        s2 += __shfl_xor(s2, m);
      }
      float mu  = s1 * (1.f / 128.f);
      float var = s2 * (1.f / 128.f) - mu * mu;
      float rs  = rsqrtf(var + 1e-5f);
      out[(size_t)b * 128 + tid]      = (a  - mu) * rs * ro_g[tid]      + ro_b[tid];
      out[(size_t)b * 128 + 64 + tid] = (b2 - mu) * rs * ro_g[64 + tid] + ro_b[64 + tid];
    }
  }
}

extern "C" void kernel_launch(void* const* d_in, const int* in_sizes, int n_in,
                              void* d_out, int out_size, void* d_ws, size_t ws_size,
                              hipStream_t stream) {
  const float* X   = (const float*)d_in[0];
  const float* alp = (const float*)d_in[1];
  const float* aln = (const float*)d_in[2];
  const float* wp  = (const float*)d_in[3];
  const float* wn  = (const float*)d_in[4];
  const float* lng = (const float*)d_in[5];
  const float* lnb = (const float*)d_in[6];
  const float* rog = (const float*)d_in[7];
  const float* rob = (const float*)d_in[8];
  float* out = (float*)d_out;

  unsigned short* A3 = (unsigned short*)d_ws;          // 131072 bf16 = 256 KB
  unsigned short* W3 = A3 + 131072;                    //  98304 bf16 = 192 KB

  (void)hipFuncSetAttribute(reinterpret_cast<const void*>(gnn_kernel),
                            hipFuncAttributeMaxDynamicSharedMemorySize, 81920);

  prep_kernel<<<448, 512, 0, stream>>>(alp, aln, wp, wn, A3, W3);
  gnn_kernel<<<2048, 256, 81920, stream>>>(X, A3, W3, lng, lnb, rog, rob, out);
}

// Round 11
// 937.630 us; speedup vs baseline: 13.3294x; 1.0121x over previous
//
#include <hip/hip_runtime.h>
#include <math.h>

// HeterogeneousGNN fused kernel for MI355X (gfx950) — round 11.
// R10 result: 256-thread WG -> 236 VGPR, ZERO spills (WRITE=1MB), 949 us.
// R10 limiter: LDS 80 KB = exactly half the 160 KB pool -> only 1 block/CU
// resident (Occupancy 12% = 4 waves/CU, 1 wave/SIMD) -> all latency exposed
// (MfmaUtil 12%). R11: v-chunks of 32 -> Gc = [128 o][80 B rows] = 10 KB,
// LDS 74 KB -> 2 blocks/CU. 80-B row stride: slot = 5*o mod 8 covers all 8
// 16B-slots -> 4-way floor with NO xor swizzle. W frags hoisted per (l,h)
// (reused by all 8 chunks; R10 re-loaded them every chunk).

typedef float  f32x4  __attribute__((ext_vector_type(4)));
typedef float  f32x16 __attribute__((ext_vector_type(16)));
typedef short  s16x8  __attribute__((ext_vector_type(8)));
typedef __bf16 bf16x8 __attribute__((ext_vector_type(8)));

#define GOFF 65536   // Gc region byte offset (10240 B)

__device__ __forceinline__ unsigned short f2bf(float f) {
  unsigned int u = __builtin_bit_cast(unsigned int, f);
  u = (u + 0x7fffu + ((u >> 16) & 1u)) >> 16;   // round-to-nearest-even
  return (unsigned short)u;
}
__device__ __forceinline__ float bf2f(unsigned short h) {
  return __builtin_bit_cast(float, (unsigned int)h << 16);
}

// H: [256 v][128 d] bf16; XOR (v&15) -> 32-lane column b128 reads 2-way (free).
__device__ __forceinline__ int haddr(int v, int d) {
  return v * 256 + ((d * 2) ^ ((v & 15) << 4));
}
// Gc^T: [128 o][32 v] bf16, 80-B row stride (64 B data + 16 pad).
// slot(o) = 5*o mod 8 -> all 8 slots -> 4-way b128 floor, no xor needed.
__device__ __forceinline__ int gaddr(int o, int vr) {
  return GOFF + o * 80 + vr * 2;
}

#define MFMA32(a, b, c) __builtin_amdgcn_mfma_f32_32x32x16_bf16( \
    __builtin_bit_cast(bf16x8, (a)), __builtin_bit_cast(bf16x8, (b)), (c), 0, 0, 0)

// ---- prep: fragment-ordered A3 / W3 (bf16) ----
// A3[h][ut 0..7][vt 0..15][lane][j] = Ac_h[u=ut*32+(lane&31)][v=vt*16+(lane>>5)*8+j]
// W3[hw 0..5][ot 0..3][kt 0..7][lane][j] = W_hw[o=ot*32+(lane&31)][d=kt*16+(lane>>5)*8+j]
__global__ void prep_kernel(const float* __restrict__ alp, const float* __restrict__ aln,
                            const float* __restrict__ wp,  const float* __restrict__ wn,
                            unsigned short* __restrict__ A3, unsigned short* __restrict__ W3) {
  int idx = blockIdx.x * 512 + threadIdx.x;     // 229376 threads total
  if (idx < 131072) {
    int j = idx & 7, lane = (idx >> 3) & 63, vt = (idx >> 9) & 15,
        ut = (idx >> 13) & 7, h = (idx >> 16) & 1;
    int u = ut * 32 + (lane & 31);
    int v = vt * 16 + (lane >> 5) * 8 + j;
    int s = u * 256 + v;
    float ap = 1.f / (1.f + expf(-alp[s]));
    float an = 1.f / (1.f + expf(-aln[s]));
    bool  m  = ap > an;
    float val = h ? (m ? 0.f : -an) : (m ? ap : 0.f);   // neg sign folded
    A3[idx] = f2bf(val);
  } else {
    int k = idx - 131072;                       // 0 .. 98303
    int j = k & 7, lane = (k >> 3) & 63, kt = (k >> 9) & 7,
        ot = (k >> 12) & 3, hw = (k >> 14);     // hw = l*2 + (0=pos,1=neg)
    int o = ot * 32 + (lane & 31);
    int d = kt * 16 + (lane >> 5) * 8 + j;
    const float* src = (hw & 1) ? wn : wp;
    W3[k] = f2bf(src[(hw >> 1) * 16384 + o * 128 + d]);
  }
}

__global__ __launch_bounds__(256, 1) void gnn_kernel(
    const float* __restrict__ X,
    const unsigned short* __restrict__ A3,
    const unsigned short* __restrict__ W3,
    const float* __restrict__ ln_g, const float* __restrict__ ln_b,
    const float* __restrict__ ro_g, const float* __restrict__ ro_b,
    float* __restrict__ out) {
  extern __shared__ char smem[];
  const int tid  = threadIdx.x;
  const int wid  = tid >> 6;        // 0..3
  const int lane = tid & 63;
  const int l31  = lane & 31;
  const int hi   = lane >> 5;
  const int b    = blockIdx.x;

  // ---- stage H = bf16(X[b]) into LDS ----
  {
    const float4* Xb = (const float4*)(X + (size_t)b * 256 * 128);
#pragma unroll 8
    for (int i = 0; i < 32; ++i) {
      int idx = tid + i * 256;                 // 8192 float4 chunks
      int v = idx >> 5, d = (idx & 31) * 4;
      float4 f = Xb[idx];
      ushort4 p;
      p.x = f2bf(f.x); p.y = f2bf(f.y); p.z = f2bf(f.z); p.w = f2bf(f.w);
      *(ushort4*)(smem + haddr(v, d)) = p;
    }
  }
  __syncthreads();

  f32x16 acc[2][4];                  // wave tile: u = wid*64..+64, o = 0..128
  for (int l = 0; l < 3; ++l) {
#pragma unroll
    for (int mt = 0; mt < 2; ++mt)
#pragma unroll
      for (int nt = 0; nt < 4; ++nt)
#pragma unroll
        for (int r = 0; r < 16; ++r) acc[mt][nt][r] = 0.f;

    for (int h = 0; h < 2; ++h) {
      const unsigned short* Wb = W3 + (size_t)(((l * 2 + h) * 4 + wid) * 8) * 512;
      const unsigned short* Ab = A3 + (size_t)((h * 8 + wid * 2) * 16) * 512;

      // hoist this (l,h,wave)'s W o-tile fragments: reused by all 8 chunks
      s16x8 wreg[8];
#pragma unroll
      for (int kt = 0; kt < 8; ++kt)
        wreg[kt] = *(const s16x8*)(Wb + (size_t)kt * 512 + lane * 8);

      for (int c = 0; c < 8; ++c) {            // v-chunks of 32 nodes
        // ---- GEMM1: Gc[32v][128o] = H[c] @ W^T; one 32x32 tile per wave ----
        f32x16 g0;
#pragma unroll
        for (int r = 0; r < 16; ++r) g0[r] = 0.f;
        const int v0 = c * 32 + l31;
#pragma unroll
        for (int kt = 0; kt < 8; ++kt) {       // K = d = 128
          s16x8 ha = *(const s16x8*)(smem + haddr(v0, kt * 16 + hi * 8));
          g0 = MFMA32(ha, wreg[kt], g0);
        }
        __syncthreads();                       // prev chunk's GEMM2 reads done
        {
          const int og = wid * 32 + l31;       // C/D col = lane&31
#pragma unroll
          for (int rq = 0; rq < 4; ++rq) {     // rows v = (r&3)+8*(r>>2)+4*hi
            int vr = rq * 8 + hi * 4;
            ushort4 p;
            p.x = f2bf(g0[rq*4+0]); p.y = f2bf(g0[rq*4+1]);
            p.z = f2bf(g0[rq*4+2]); p.w = f2bf(g0[rq*4+3]);
            *(ushort4*)(smem + gaddr(og, vr)) = p;
          }
        }
        __syncthreads();                       // Gc ready

        // ---- GEMM2: acc += Ac_h[u, 32c..] @ Gc; 64u x 128o per wave ----
#pragma unroll
        for (int kt = 0; kt < 2; ++kt) {       // K = v-chunk = 32
          s16x8 bf[4];
#pragma unroll
          for (int nt = 0; nt < 4; ++nt)
            bf[nt] = *(const s16x8*)(smem + gaddr(nt * 32 + l31, kt * 16 + hi * 8));
          s16x8 a0 = *(const s16x8*)(Ab + (size_t)(0 * 16 + c * 2 + kt) * 512 + lane * 8);
          s16x8 a1 = *(const s16x8*)(Ab + (size_t)(1 * 16 + c * 2 + kt) * 512 + lane * 8);
#pragma unroll
          for (int nt = 0; nt < 4; ++nt) {
            acc[0][nt] = MFMA32(a0, bf[nt], acc[0][nt]);
            acc[1][nt] = MFMA32(a1, bf[nt], acc[1][nt]);
          }
        }
      } // chunks
    } // halves

    // ---- epilogue: exact GELU + wave-local LayerNorm -> H ----
    {
      float lg[4], lb[4];
#pragma unroll
      for (int nt = 0; nt < 4; ++nt) {
        lg[nt] = ln_g[l * 128 + nt * 32 + l31];
        lb[nt] = ln_b[l * 128 + nt * 32 + l31];
      }
#pragma unroll
      for (int mt = 0; mt < 2; ++mt)
#pragma unroll
        for (int r = 0; r < 16; ++r) {
          float x0 = acc[mt][0][r]; x0 = 0.5f * x0 * (1.f + erff(x0 * 0.70710678f));
          float x1 = acc[mt][1][r]; x1 = 0.5f * x1 * (1.f + erff(x1 * 0.70710678f));
          float x2 = acc[mt][2][r]; x2 = 0.5f * x2 * (1.f + erff(x2 * 0.70710678f));
          float x3 = acc[mt][3][r]; x3 = 0.5f * x3 * (1.f + erff(x3 * 0.70710678f));
          acc[mt][0][r] = x0; acc[mt][1][r] = x1;
          acc[mt][2][r] = x2; acc[mt][3][r] = x3;
          float s1 = x0 + x1 + x2 + x3;
          float s2 = x0 * x0 + x1 * x1 + x2 * x2 + x3 * x3;
#pragma unroll
          for (int m = 1; m < 32; m <<= 1) {   // full row (128 cols) reduce
            s1 += __shfl_xor(s1, m);
            s2 += __shfl_xor(s2, m);
          }
          float mu  = s1 * (1.f / 128.f);
          float var = s2 * (1.f / 128.f) - mu * mu;
          float rs  = rsqrtf(var + 1e-5f);
          int u = wid * 64 + mt * 32 + (r & 3) + 8 * ((r >> 2) & 3) + 4 * hi;
#pragma unroll
          for (int nt = 0; nt < 4; ++nt) {
            float y = (acc[mt][nt][r] - mu) * rs * lg[nt] + lb[nt];
            *(unsigned short*)(smem + haddr(u, nt * 32 + l31)) = f2bf(y);
          }
        }
    }
    __syncthreads();                           // H' ready for next layer
  } // layers

  // ---- readout: mean over nodes + final LN ----
  {
    int d   = tid & 127;
    int grp = tid >> 7;                        // 0..1, 128 rows each
    float s = 0.f;
    for (int v = grp * 128; v < grp * 128 + 128; ++v)
      s += bf2f(*(const unsigned short*)(smem + haddr(v, d)));
    float* red = (float*)(smem + GOFF);        // Gc region is dead now
    red[grp * 128 + d] = s;
    __syncthreads();
    if (tid < 128) {
      red[256 + tid] = (red[tid] + red[128 + tid]) * (1.f / 256.f);
    }
    __syncthreads();
    if (tid < 64) {
      float a  = red[256 + tid];
      float b2 = red[256 + 64 + tid];
      float s1 = a + b2, s2 = a * a + b2 * b2;
#pragma unroll
      for (int m = 1; m < 64; m <<= 1) {
        s1 += __shfl_xor(s1, m);
        s2 += __shfl_xor(s2, m);
      }
      float mu  = s1 * (1.f / 128.f);
      float var = s2 * (1.f / 128.f) - mu * mu;
      float rs  = rsqrtf(var + 1e-5f);
      out[(size_t)b * 128 + tid]      = (a  - mu) * rs * ro_g[tid]      + ro_b[tid];
      out[(size_t)b * 128 + 64 + tid] = (b2 - mu) * rs * ro_g[64 + tid] + ro_b[64 + tid];
    }
  }
}

extern "C" void kernel_launch(void* const* d_in, const int* in_sizes, int n_in,
                              void* d_out, int out_size, void* d_ws, size_t ws_size,
                              hipStream_t stream) {
  const float* X   = (const float*)d_in[0];
  const float* alp = (const float*)d_in[1];
  const float* aln = (const float*)d_in[2];
  const float* wp  = (const float*)d_in[3];
  const float* wn  = (const float*)d_in[4];
  const float* lng = (const float*)d_in[5];
  const float* lnb = (const float*)d_in[6];
  const float* rog = (const float*)d_in[7];
  const float* rob = (const float*)d_in[8];
  float* out = (float*)d_out;

  unsigned short* A3 = (unsigned short*)d_ws;          // 131072 bf16 = 256 KB
  unsigned short* W3 = A3 + 131072;                    //  98304 bf16 = 192 KB

  (void)hipFuncSetAttribute(reinterpret_cast<const void*>(gnn_kernel),
                            hipFuncAttributeMaxDynamicSharedMemorySize, 75776);

  prep_kernel<<<448, 512, 0, stream>>>(alp, aln, wp, wn, A3, W3);
  gnn_kernel<<<2048, 256, 75776, stream>>>(X, A3, W3, lng, lnb, rog, rob, out);
}

// Round 12
// 701.436 us; speedup vs baseline: 17.8178x; 1.3367x over previous
//
#include <hip/hip_runtime.h>
#include <math.h>

// HeterogeneousGNN fused kernel for MI355X (gfx950) — round 12.
// R11 decode: occupancy pinned at 12.5% (1 wave/SIMD) because unified-file
// total = VGPR_Count(220) + AGPR acc(128) ~ 348 > 256 -> only one wave fits
// the 512-reg file per SIMD. LDS (74 KB) already allows 2 blocks/CU.
// Single change vs R11: __launch_bounds__(256, 2) -> 256-reg/wave cap
// (empirical decode: cap = 131072/(threads*arg2)). Demand ~226 (acc 128 AGPR
// + wreg 32 + gacc 16 + windows ~30 + addr ~20) fits WITHOUT spilling ->
// 2 blocks/CU, 2 waves/SIMD, cross-block latency hiding (m114).

typedef float  f32x4  __attribute__((ext_vector_type(4)));
typedef float  f32x16 __attribute__((ext_vector_type(16)));
typedef short  s16x8  __attribute__((ext_vector_type(8)));
typedef __bf16 bf16x8 __attribute__((ext_vector_type(8)));

#define GOFF 65536   // Gc region byte offset (10240 B)

__device__ __forceinline__ unsigned short f2bf(float f) {
  unsigned int u = __builtin_bit_cast(unsigned int, f);
  u = (u + 0x7fffu + ((u >> 16) & 1u)) >> 16;   // round-to-nearest-even
  return (unsigned short)u;
}
__device__ __forceinline__ float bf2f(unsigned short h) {
  return __builtin_bit_cast(float, (unsigned int)h << 16);
}

// H: [256 v][128 d] bf16; XOR (v&15) -> 32-lane column b128 reads 2-way (free).
__device__ __forceinline__ int haddr(int v, int d) {
  return v * 256 + ((d * 2) ^ ((v & 15) << 4));
}
// Gc^T: [128 o][32 v] bf16, 80-B row stride (64 B data + 16 pad).
// slot(o) = 5*o mod 8 -> all 8 slots -> 4-way b128 floor, no xor needed.
__device__ __forceinline__ int gaddr(int o, int vr) {
  return GOFF + o * 80 + vr * 2;
}

#define MFMA32(a, b, c) __builtin_amdgcn_mfma_f32_32x32x16_bf16( \
    __builtin_bit_cast(bf16x8, (a)), __builtin_bit_cast(bf16x8, (b)), (c), 0, 0, 0)

// ---- prep: fragment-ordered A3 / W3 (bf16) ----
// A3[h][ut 0..7][vt 0..15][lane][j] = Ac_h[u=ut*32+(lane&31)][v=vt*16+(lane>>5)*8+j]
// W3[hw 0..5][ot 0..3][kt 0..7][lane][j] = W_hw[o=ot*32+(lane&31)][d=kt*16+(lane>>5)*8+j]
__global__ void prep_kernel(const float* __restrict__ alp, const float* __restrict__ aln,
                            const float* __restrict__ wp,  const float* __restrict__ wn,
                            unsigned short* __restrict__ A3, unsigned short* __restrict__ W3) {
  int idx = blockIdx.x * 512 + threadIdx.x;     // 229376 threads total
  if (idx < 131072) {
    int j = idx & 7, lane = (idx >> 3) & 63, vt = (idx >> 9) & 15,
        ut = (idx >> 13) & 7, h = (idx >> 16) & 1;
    int u = ut * 32 + (lane & 31);
    int v = vt * 16 + (lane >> 5) * 8 + j;
    int s = u * 256 + v;
    float ap = 1.f / (1.f + expf(-alp[s]));
    float an = 1.f / (1.f + expf(-aln[s]));
    bool  m  = ap > an;
    float val = h ? (m ? 0.f : -an) : (m ? ap : 0.f);   // neg sign folded
    A3[idx] = f2bf(val);
  } else {
    int k = idx - 131072;                       // 0 .. 98303
    int j = k & 7, lane = (k >> 3) & 63, kt = (k >> 9) & 7,
        ot = (k >> 12) & 3, hw = (k >> 14);     // hw = l*2 + (0=pos,1=neg)
    int o = ot * 32 + (lane & 31);
    int d = kt * 16 + (lane >> 5) * 8 + j;
    const float* src = (hw & 1) ? wn : wp;
    W3[k] = f2bf(src[(hw >> 1) * 16384 + o * 128 + d]);
  }
}

__global__ __launch_bounds__(256, 2) void gnn_kernel(
    const float* __restrict__ X,
    const unsigned short* __restrict__ A3,
    const unsigned short* __restrict__ W3,
    const float* __restrict__ ln_g, const float* __restrict__ ln_b,
    const float* __restrict__ ro_g, const float* __restrict__ ro_b,
    float* __restrict__ out) {
  extern __shared__ char smem[];
  const int tid  = threadIdx.x;
  const int wid  = tid >> 6;        // 0..3
  const int lane = tid & 63;
  const int l31  = lane & 31;
  const int hi   = lane >> 5;
  const int b    = blockIdx.x;

  // ---- stage H = bf16(X[b]) into LDS ----
  {
    const float4* Xb = (const float4*)(X + (size_t)b * 256 * 128);
#pragma unroll 8
    for (int i = 0; i < 32; ++i) {
      int idx = tid + i * 256;                 // 8192 float4 chunks
      int v = idx >> 5, d = (idx & 31) * 4;
      float4 f = Xb[idx];
      ushort4 p;
      p.x = f2bf(f.x); p.y = f2bf(f.y); p.z = f2bf(f.z); p.w = f2bf(f.w);
      *(ushort4*)(smem + haddr(v, d)) = p;
    }
  }
  __syncthreads();

  f32x16 acc[2][4];                  // wave tile: u = wid*64..+64, o = 0..128
  for (int l = 0; l < 3; ++l) {
#pragma unroll
    for (int mt = 0; mt < 2; ++mt)
#pragma unroll
      for (int nt = 0; nt < 4; ++nt)
#pragma unroll
        for (int r = 0; r < 16; ++r) acc[mt][nt][r] = 0.f;

    for (int h = 0; h < 2; ++h) {
      const unsigned short* Wb = W3 + (size_t)(((l * 2 + h) * 4 + wid) * 8) * 512;
      const unsigned short* Ab = A3 + (size_t)((h * 8 + wid * 2) * 16) * 512;

      // hoist this (l,h,wave)'s W o-tile fragments: reused by all 8 chunks
      s16x8 wreg[8];
#pragma unroll
      for (int kt = 0; kt < 8; ++kt)
        wreg[kt] = *(const s16x8*)(Wb + (size_t)kt * 512 + lane * 8);

      for (int c = 0; c < 8; ++c) {            // v-chunks of 32 nodes
        // ---- GEMM1: Gc[32v][128o] = H[c] @ W^T; one 32x32 tile per wave ----
        f32x16 g0;
#pragma unroll
        for (int r = 0; r < 16; ++r) g0[r] = 0.f;
        const int v0 = c * 32 + l31;
#pragma unroll
        for (int kt = 0; kt < 8; ++kt) {       // K = d = 128
          s16x8 ha = *(const s16x8*)(smem + haddr(v0, kt * 16 + hi * 8));
          g0 = MFMA32(ha, wreg[kt], g0);
        }
        __syncthreads();                       // prev chunk's GEMM2 reads done
        {
          const int og = wid * 32 + l31;       // C/D col = lane&31
#pragma unroll
          for (int rq = 0; rq < 4; ++rq) {     // rows v = (r&3)+8*(r>>2)+4*hi
            int vr = rq * 8 + hi * 4;
            ushort4 p;
            p.x = f2bf(g0[rq*4+0]); p.y = f2bf(g0[rq*4+1]);
            p.z = f2bf(g0[rq*4+2]); p.w = f2bf(g0[rq*4+3]);
            *(ushort4*)(smem + gaddr(og, vr)) = p;
          }
        }
        __syncthreads();                       // Gc ready

        // ---- GEMM2: acc += Ac_h[u, 32c..] @ Gc; 64u x 128o per wave ----
#pragma unroll
        for (int kt = 0; kt < 2; ++kt) {       // K = v-chunk = 32
          s16x8 bf[4];
#pragma unroll
          for (int nt = 0; nt < 4; ++nt)
            bf[nt] = *(const s16x8*)(smem + gaddr(nt * 32 + l31, kt * 16 + hi * 8));
          s16x8 a0 = *(const s16x8*)(Ab + (size_t)(0 * 16 + c * 2 + kt) * 512 + lane * 8);
          s16x8 a1 = *(const s16x8*)(Ab + (size_t)(1 * 16 + c * 2 + kt) * 512 + lane * 8);
#pragma unroll
          for (int nt = 0; nt < 4; ++nt) {
            acc[0][nt] = MFMA32(a0, bf[nt], acc[0][nt]);
            acc[1][nt] = MFMA32(a1, bf[nt], acc[1][nt]);
          }
        }
      } // chunks
    } // halves

    // ---- epilogue: exact GELU + wave-local LayerNorm -> H ----
    {
      float lg[4], lb[4];
#pragma unroll
      for (int nt = 0; nt < 4; ++nt) {
        lg[nt] = ln_g[l * 128 + nt * 32 + l31];
        lb[nt] = ln_b[l * 128 + nt * 32 + l31];
      }
#pragma unroll
      for (int mt = 0; mt < 2; ++mt)
#pragma unroll
        for (int r = 0; r < 16; ++r) {
          float x0 = acc[mt][0][r]; x0 = 0.5f * x0 * (1.f + erff(x0 * 0.70710678f));
          float x1 = acc[mt][1][r]; x1 = 0.5f * x1 * (1.f + erff(x1 * 0.70710678f));
          float x2 = acc[mt][2][r]; x2 = 0.5f * x2 * (1.f + erff(x2 * 0.70710678f));
          float x3 = acc[mt][3][r]; x3 = 0.5f * x3 * (1.f + erff(x3 * 0.70710678f));
          acc[mt][0][r] = x0; acc[mt][1][r] = x1;
          acc[mt][2][r] = x2; acc[mt][3][r] = x3;
          float s1 = x0 + x1 + x2 + x3;
          float s2 = x0 * x0 + x1 * x1 + x2 * x2 + x3 * x3;
#pragma unroll
          for (int m = 1; m < 32; m <<= 1) {   // full row (128 cols) reduce
            s1 += __shfl_xor(s1, m);
            s2 += __shfl_xor(s2, m);
          }
          float mu  = s1 * (1.f / 128.f);
          float var = s2 * (1.f / 128.f) - mu * mu;
          float rs  = rsqrtf(var + 1e-5f);
          int u = wid * 64 + mt * 32 + (r & 3) + 8 * ((r >> 2) & 3) + 4 * hi;
#pragma unroll
          for (int nt = 0; nt < 4; ++nt) {
            float y = (acc[mt][nt][r] - mu) * rs * lg[nt] + lb[nt];
            *(unsigned short*)(smem + haddr(u, nt * 32 + l31)) = f2bf(y);
          }
        }
    }
    __syncthreads();                           // H' ready for next layer
  } // layers

  // ---- readout: mean over nodes + final LN ----
  {
    int d   = tid & 127;
    int grp = tid >> 7;                        // 0..1, 128 rows each
    float s = 0.f;
    for (int v = grp * 128; v < grp * 128 + 128; ++v)
      s += bf2f(*(const unsigned short*)(smem + haddr(v, d)));
    float* red = (float*)(smem + GOFF);        // Gc region is dead now
    red[grp * 128 + d] = s;
    __syncthreads();
    if (tid < 128) {
      red[256 + tid] = (red[tid] + red[128 + tid]) * (1.f / 256.f);
    }
    __syncthreads();
    if (tid < 64) {
      float a  = red[256 + tid];
      float b2 = red[256 + 64 + tid];
      float s1 = a + b2, s2 = a * a + b2 * b2;
#pragma unroll
      for (int m = 1; m < 64; m <<= 1) {
        s1 += __shfl_xor(s1, m);
        s2 += __shfl_xor(s2, m);
      }
      float mu  = s1 * (1.f / 128.f);
      float var = s2 * (1.f / 128.f) - mu * mu;
      float rs  = rsqrtf(var + 1e-5f);
      out[(size_t)b * 128 + tid]      = (a  - mu) * rs * ro_g[tid]      + ro_b[tid];
      out[(size_t)b * 128 + 64 + tid] = (b2 - mu) * rs * ro_g[64 + tid] + ro_b[64 + tid];
    }
  }
}

extern "C" void kernel_launch(void* const* d_in, const int* in_sizes, int n_in,
                              void* d_out, int out_size, void* d_ws, size_t ws_size,
                              hipStream_t stream) {
  const float* X   = (const float*)d_in[0];
  const float* alp = (const float*)d_in[1];
  const float* aln = (const float*)d_in[2];
  const float* wp  = (const float*)d_in[3];
  const float* wn  = (const float*)d_in[4];
  const float* lng = (const float*)d_in[5];
  const float* lnb = (const float*)d_in[6];
  const float* rog = (const float*)d_in[7];
  const float* rob = (const float*)d_in[8];
  float* out = (float*)d_out;

  unsigned short* A3 = (unsigned short*)d_ws;          // 131072 bf16 = 256 KB
  unsigned short* W3 = A3 + 131072;                    //  98304 bf16 = 192 KB

  (void)hipFuncSetAttribute(reinterpret_cast<const void*>(gnn_kernel),
                            hipFuncAttributeMaxDynamicSharedMemorySize, 75776);

  prep_kernel<<<448, 512, 0, stream>>>(alp, aln, wp, wn, A3, W3);
  gnn_kernel<<<2048, 256, 75776, stream>>>(X, A3, W3, lng, lnb, rog, rob, out);
}